// Round 8
// baseline (321.549 us; speedup 1.0000x reference)
//
#include <hip/hip_runtime.h>
#include <hip/hip_bf16.h>

#define N_NODES 32768
#define DEG 16
#define E_EDGES (N_NODES * DEG)
#define HEADS 4
#define OUT_D 64
#define HD 256            // HEADS*OUT_D
#define SLOPE 0.2f
#define GMARG 0.1f
#define CMARG 0.1f
#define NUM_LOSS_BLOCKS 8192   // N_NODES/4

typedef float f32x4 __attribute__((ext_vector_type(4)));
typedef unsigned short ushort4v __attribute__((ext_vector_type(4)));

__device__ __forceinline__ float bf2f(unsigned short u) {
    return __uint_as_float(((unsigned int)u) << 16);
}
__device__ __forceinline__ unsigned short f2bf(float x) {
    __hip_bfloat16 h = __float2bfloat16(x);   // RNE
    return __builtin_bit_cast(unsigned short, h);
}
__device__ __forceinline__ float leaky(float x) {
    return x >= 0.f ? x : SLOPE * x;
}

__global__ void badcfg_kernel(float* out, float code) {
    out[0] = code;
}

// ---------------------------------------------------------------------------
// K0: transpose W [c][k] fp32 -> Wt [k][c] fp32  (256x256)  [fs = feat @ W.T]
// ---------------------------------------------------------------------------
__global__ __launch_bounds__(256) void transw_kernel(const float* __restrict__ W,
                                                     float* __restrict__ Wt) {
    const int c = blockIdx.x * 4 + (threadIdx.x >> 6);
    const int t = threadIdx.x & 63;
    f32x4 v = *(const f32x4*)(W + (size_t)c * HD + t * 4);
#pragma unroll
    for (int j = 0; j < 4; ++j)
        Wt[(size_t)(t * 4 + j) * HD + c] = v[j];
}

// ---------------------------------------------------------------------------
// K1: fs = feat @ W^T, fp32 VALU, stored bf16. 64-node tile in LDS.
// ---------------------------------------------------------------------------
__global__ __launch_bounds__(256) void gemm_kernel(const float* __restrict__ feat,
                                                   const float* __restrict__ Wt,
                                                   unsigned short* __restrict__ fsb) {
    __shared__ float lds[64 * HD];   // 64 KB
    const int tid = threadIdx.x;
    const int n0 = blockIdx.x * 64;
#pragma unroll
    for (int rep = 0; rep < 16; ++rep) {
        const int idx = rep * 1024 + tid * 4;
        *(f32x4*)(lds + idx) = *(const f32x4*)(feat + (size_t)n0 * HD + idx);
    }
    __syncthreads();
    const int c = tid;
    f32x4 acc[16];
#pragma unroll
    for (int i = 0; i < 16; ++i) acc[i] = (f32x4)(0.f);
    for (int k4 = 0; k4 < 64; ++k4) {
        f32x4 w;
#pragma unroll
        for (int j = 0; j < 4; ++j)
            w[j] = Wt[(size_t)(k4 * 4 + j) * HD + c];
#pragma unroll
        for (int i = 0; i < 16; ++i) {
#pragma unroll
            for (int j = 0; j < 4; ++j) {
                f32x4 f = *(const f32x4*)(lds + (i * 4 + j) * HD + k4 * 4);
                acc[i][j] += f[0] * w[0] + f[1] * w[1] + f[2] * w[2] + f[3] * w[3];
            }
        }
    }
#pragma unroll
    for (int i = 0; i < 16; ++i)
#pragma unroll
        for (int j = 0; j < 4; ++j)
            fsb[(size_t)(n0 + i * 4 + j) * HD + c] = f2bf(acc[i][j]);
}

// ---------------------------------------------------------------------------
// K2: el[n,h]=sum_d fs[n,h,d]*attn_l[h,d]; er same with attn_r (h-major attn)
// ---------------------------------------------------------------------------
__global__ __launch_bounds__(256) void elr_kernel(const unsigned short* __restrict__ fsb,
                                                  const float* __restrict__ attn_l,
                                                  const float* __restrict__ attn_r,
                                                  float* __restrict__ el,
                                                  float* __restrict__ er) {
    const int wave = threadIdx.x >> 6;
    const int lane = threadIdx.x & 63;
    const int n = blockIdx.x * 4 + wave;
    const int i = lane * 4;
    ushort4v u = *(const ushort4v*)(fsb + (size_t)n * HD + i);
    f32x4 al = *(const f32x4*)(attn_l + i);
    f32x4 ar = *(const f32x4*)(attn_r + i);
    float v0 = bf2f(u[0]), v1 = bf2f(u[1]), v2 = bf2f(u[2]), v3 = bf2f(u[3]);
    float sl = v0 * al[0] + v1 * al[1] + v2 * al[2] + v3 * al[3];
    float sr = v0 * ar[0] + v1 * ar[1] + v2 * ar[2] + v3 * ar[3];
#pragma unroll
    for (int mask = 1; mask < 16; mask <<= 1) {
        sl += __shfl_xor(sl, mask, 64);
        sr += __shfl_xor(sr, mask, 64);
    }
    if ((lane & 15) == 0) {
        el[n * 4 + (lane >> 4)] = sl;
        er[n * 4 + (lane >> 4)] = sr;
    }
}

// ---------------------------------------------------------------------------
// K3: Lg/Lb partials (pw/nw on the fly)
// ---------------------------------------------------------------------------
__global__ __launch_bounds__(256) void loss_kernel(const int* __restrict__ src,
                                                   const int* __restrict__ dst,
                                                   const int* __restrict__ perm,
                                                   const int* __restrict__ label,
                                                   const float* __restrict__ el,
                                                   const float* __restrict__ er,
                                                   float* __restrict__ partials) {
    const int wave = threadIdx.x >> 6;
    const int lane = threadIdx.x & 63;
    const int n = blockIdx.x * 4 + wave;
    const int a = lane >> 2;
    const int h = lane & 3;
    const int e = n * DEG + a;
    const int s = src[e];
    const int d = dst[e];
    const int p = perm[e];
    const int nd = dst[p];
    const float els = el[s * 4 + h];
    const float pwa = leaky(els + er[d * 4 + h]);
    const float nwa = leaky(els + er[nd * 4 + h]);
    const int adja = (label[s] == label[d]) ? 1 : 0;
    float lg = 0.f, lb = 0.f;
#pragma unroll
    for (int b = 0; b < 16; ++b) {
        const int srcl = b * 4 + h;
        float pwb = __shfl(pwa, srcl, 64);
        int adjb = __shfl(adja, srcl, 64);
        lg += fmaxf(nwa + GMARG - pwb, 0.f);
        if (adja && !adjb) lb += fmaxf(pwb + CMARG - pwa, 0.f);
    }
#pragma unroll
    for (int mask = 1; mask < 64; mask <<= 1) {
        lg += __shfl_xor(lg, mask, 64);
        lb += __shfl_xor(lb, mask, 64);
    }
    __shared__ float slg[4], slb[4];
    if (lane == 0) { slg[wave] = lg; slb[wave] = lb; }
    __syncthreads();
    if (threadIdx.x == 0) {
        partials[blockIdx.x * 2]     = slg[0] + slg[1] + slg[2] + slg[3];
        partials[blockIdx.x * 2 + 1] = slb[0] + slb[1] + slb[2] + slb[3];
    }
}

// ---------------------------------------------------------------------------
// K4: softmax over DEG + gather-sum -> rst (FP32 out)
// ---------------------------------------------------------------------------
__global__ __launch_bounds__(256) void aggregate_kernel(const int* __restrict__ src,
                                                        const float* __restrict__ el,
                                                        const float* __restrict__ er,
                                                        const unsigned short* __restrict__ fsb,
                                                        float* __restrict__ out) {
    __shared__ float a_sm[DEG * HEADS];
    __shared__ int sidx[DEG];
    const int n = blockIdx.x;
    const int tid = threadIdx.x;
    if (tid < DEG) sidx[tid] = src[n * DEG + tid];
    __syncthreads();
    if (tid < 64) {
        const int j = tid >> 2, h = tid & 3;
        a_sm[j * 4 + h] = leaky(el[sidx[j] * 4 + h] + er[n * 4 + h]);
    }
    __syncthreads();
    if (tid < HEADS) {
        const int h = tid;
        float mx = -1e30f;
#pragma unroll
        for (int j = 0; j < DEG; ++j) mx = fmaxf(mx, a_sm[j * 4 + h]);
        float s = 0.f;
#pragma unroll
        for (int j = 0; j < DEG; ++j) {
            float ee = __expf(a_sm[j * 4 + h] - mx);
            a_sm[j * 4 + h] = ee;
            s += ee;
        }
        const float inv = 1.f / s;
#pragma unroll
        for (int j = 0; j < DEG; ++j) a_sm[j * 4 + h] *= inv;
    }
    __syncthreads();
    const int h = tid >> 6;
    float acc = 0.f;
#pragma unroll
    for (int j = 0; j < DEG; ++j) {
        acc += a_sm[j * 4 + h] * bf2f(fsb[(size_t)sidx[j] * HD + tid]);
    }
    out[(size_t)n * HD + tid] = acc;   // FP32 output
}

// ---------------------------------------------------------------------------
// K5: reduce partials -> Lg, Lb (FP32 scalars; double accumulation)
// ---------------------------------------------------------------------------
__global__ __launch_bounds__(256) void finalize_kernel(const float* __restrict__ partials,
                                                       float* __restrict__ out) {
    const int tid = threadIdx.x;
    const int lane = tid & 63;
    const int wave = tid >> 6;
    double lg = 0.0, lb = 0.0;
    for (int i = tid; i < NUM_LOSS_BLOCKS; i += 256) {
        lg += (double)partials[i * 2];
        lb += (double)partials[i * 2 + 1];
    }
#pragma unroll
    for (int mask = 1; mask < 64; mask <<= 1) {
        lg += __shfl_xor(lg, mask, 64);
        lb += __shfl_xor(lb, mask, 64);
    }
    __shared__ double slg[4], slb[4];
    if (lane == 0) { slg[wave] = lg; slb[wave] = lb; }
    __syncthreads();
    if (tid == 0) {
        const double scale = 1.0 / (double)((size_t)N_NODES * HEADS);
        out[(size_t)N_NODES * HD]     = (float)((slg[0] + slg[1] + slg[2] + slg[3]) * scale);
        out[(size_t)N_NODES * HD + 1] = (float)((slb[0] + slb[1] + slb[2] + slb[3]) * scale);
    }
}

extern "C" void kernel_launch(void* const* d_in, const int* in_sizes, int n_in,
                              void* d_out, int out_size, void* d_ws, size_t ws_size,
                              hipStream_t stream) {
    const float* feat   = (const float*)d_in[0];
    const int*   label  = (const int*)d_in[1];
    const int*   src    = (const int*)d_in[2];
    const int*   dst    = (const int*)d_in[3];
    const int*   perm   = (const int*)d_in[4];
    const float* W      = (const float*)d_in[5];
    const float* attn_l = (const float*)d_in[6];
    const float* attn_r = (const float*)d_in[7];
    float* out = (float*)d_out;   // R8: FP32 output

    const int expect[8] = {8388608, 32768, 524288, 524288, 524288, 65536, 256, 256};
    if (n_in != 8) {
        hipLaunchKernelGGL(badcfg_kernel, dim3(1), dim3(1), 0, stream, out, 60000.f);
        return;
    }
    for (int i = 0; i < 8; ++i) {
        if (in_sizes[i] != expect[i]) {
            hipLaunchKernelGGL(badcfg_kernel, dim3(1), dim3(1), 0, stream, out,
                               65536.f + 256.f * (float)i);
            return;
        }
    }
    if (out_size != N_NODES * HD + 2) {
        hipLaunchKernelGGL(badcfg_kernel, dim3(1), dim3(1), 0, stream, out, 200000.f);
        return;
    }

    char* ws = (char*)d_ws;
    size_t off = 0;
    float* partials = (float*)(ws + off); off += (size_t)NUM_LOSS_BLOCKS * 2 * sizeof(float);
    off = (off + 255) & ~(size_t)255;
    float* Wt = (float*)(ws + off); off += (size_t)HD * HD * sizeof(float);
    off = (off + 255) & ~(size_t)255;
    unsigned short* fsb = (unsigned short*)(ws + off); off += (size_t)N_NODES * HD * sizeof(unsigned short);
    float* el = (float*)(ws + off); off += (size_t)N_NODES * HEADS * sizeof(float);
    float* er = (float*)(ws + off); off += (size_t)N_NODES * HEADS * sizeof(float);
    if (off > ws_size) {
        hipLaunchKernelGGL(badcfg_kernel, dim3(1), dim3(1), 0, stream, out, 131072.f);
        return;
    }

    hipLaunchKernelGGL(transw_kernel, dim3(64), dim3(256), 0, stream, W, Wt);
    hipLaunchKernelGGL(gemm_kernel, dim3(N_NODES / 64), dim3(256), 0, stream, feat, Wt, fsb);
    hipLaunchKernelGGL(elr_kernel, dim3(N_NODES / 4), dim3(256), 0, stream, fsb, attn_l, attn_r, el, er);
    hipLaunchKernelGGL(loss_kernel, dim3(NUM_LOSS_BLOCKS), dim3(256), 0, stream, src, dst, perm, label, el, er, partials);
    hipLaunchKernelGGL(aggregate_kernel, dim3(N_NODES), dim3(256), 0, stream, src, el, er, fsb, out);
    hipLaunchKernelGGL(finalize_kernel, dim3(1), dim3(256), 0, stream, partials, out);
}

// Round 9
// 206.996 us; speedup vs baseline: 1.5534x; 1.5534x over previous
//
#include <hip/hip_runtime.h>
#include <hip/hip_bf16.h>

#define N_NODES 32768
#define DEG 16
#define E_EDGES (N_NODES * DEG)
#define HEADS 4
#define OUT_D 64
#define HD 256            // HEADS*OUT_D
#define SLOPE 0.2f
#define GMARG 0.1f
#define CMARG 0.1f
#define NUM_LOSS_BLOCKS 8192   // N_NODES/4

typedef float f32x4 __attribute__((ext_vector_type(4)));
typedef unsigned short ushort4v __attribute__((ext_vector_type(4)));
typedef short bf16x8 __attribute__((ext_vector_type(8)));
typedef short short4v __attribute__((ext_vector_type(4)));

__device__ __forceinline__ float bf2f(unsigned short u) {
    return __uint_as_float(((unsigned int)u) << 16);
}
__device__ __forceinline__ unsigned short f2bf(float x) {
    __hip_bfloat16 h = __float2bfloat16(x);   // RNE
    return __builtin_bit_cast(unsigned short, h);
}
__device__ __forceinline__ short f2bf_s(float x) {
    __hip_bfloat16 h = __float2bfloat16(x);
    return __builtin_bit_cast(short, h);
}
__device__ __forceinline__ float leaky(float x) {
    return x >= 0.f ? x : SLOPE * x;
}

__global__ void badcfg_kernel(float* out, float code) {
    out[0] = code;
}

// ---------------------------------------------------------------------------
// K0: convert W [256,256] fp32 -> bf16 (into ws)
// ---------------------------------------------------------------------------
__global__ __launch_bounds__(256) void convw_kernel(const float* __restrict__ W,
                                                    short* __restrict__ Wb) {
    const int i = (blockIdx.x * 256 + threadIdx.x) * 4;
    f32x4 v = *(const f32x4*)(W + i);
    short4v o;
    o[0] = f2bf_s(v[0]); o[1] = f2bf_s(v[1]); o[2] = f2bf_s(v[2]); o[3] = f2bf_s(v[3]);
    *(short4v*)(Wb + i) = o;
}

// ---------------------------------------------------------------------------
// K1: fs = feat @ W^T via MFMA 16x16x32 bf16, out bf16.
// Wave = 16 nodes x 256 cols. A[m=lane&15][k=q*8+j] (q=lane>>4),
// B[k=q*8+j][n=lane&15] <- Wb[c=n][k] gives B=W^T. D: row=q*4+r, col=lane&15
// (HW-verified m89/m91 mapping).
// ---------------------------------------------------------------------------
__global__ __launch_bounds__(256) void gemm_kernel(const float* __restrict__ feat,
                                                   const short* __restrict__ Wb,
                                                   unsigned short* __restrict__ fsb) {
    const int wave = threadIdx.x >> 6;
    const int lane = threadIdx.x & 63;
    const int row0 = (blockIdx.x * 4 + wave) * 16;
    const int m = lane & 15;
    const int q = lane >> 4;

    // preload all 8 A fragments (K = 256 = 8 * 32), fp32 -> bf16 in-register
    bf16x8 afr[8];
    const float* arow = feat + (size_t)(row0 + m) * HD + q * 8;
#pragma unroll
    for (int kk = 0; kk < 8; ++kk) {
        f32x4 lo = *(const f32x4*)(arow + kk * 32);
        f32x4 hi = *(const f32x4*)(arow + kk * 32 + 4);
        bf16x8 a;
        a[0] = f2bf_s(lo[0]); a[1] = f2bf_s(lo[1]); a[2] = f2bf_s(lo[2]); a[3] = f2bf_s(lo[3]);
        a[4] = f2bf_s(hi[0]); a[5] = f2bf_s(hi[1]); a[6] = f2bf_s(hi[2]); a[7] = f2bf_s(hi[3]);
        afr[kk] = a;
    }

    f32x4 acc[16];
#pragma unroll
    for (int t = 0; t < 16; ++t) acc[t] = (f32x4)(0.0f);

#pragma unroll
    for (int t = 0; t < 16; ++t) {
        const short* brow = Wb + (size_t)(t * 16 + m) * HD + q * 8;
#pragma unroll
        for (int kk = 0; kk < 8; ++kk) {
            bf16x8 bfr = *(const bf16x8*)(brow + kk * 32);
            acc[t] = __builtin_amdgcn_mfma_f32_16x16x32_bf16(afr[kk], bfr, acc[t], 0, 0, 0);
        }
    }

#pragma unroll
    for (int t = 0; t < 16; ++t) {
#pragma unroll
        for (int r = 0; r < 4; ++r) {
            fsb[(size_t)(row0 + q * 4 + r) * HD + t * 16 + m] = f2bf(acc[t][r]);
        }
    }
}

// ---------------------------------------------------------------------------
// K2: el[n,h]=sum_d fs[n,h,d]*attn_l[h,d]; er same with attn_r
// ---------------------------------------------------------------------------
__global__ __launch_bounds__(256) void elr_kernel(const unsigned short* __restrict__ fsb,
                                                  const float* __restrict__ attn_l,
                                                  const float* __restrict__ attn_r,
                                                  float* __restrict__ el,
                                                  float* __restrict__ er) {
    const int wave = threadIdx.x >> 6;
    const int lane = threadIdx.x & 63;
    const int n = blockIdx.x * 4 + wave;
    const int i = lane * 4;
    ushort4v u = *(const ushort4v*)(fsb + (size_t)n * HD + i);
    f32x4 al = *(const f32x4*)(attn_l + i);
    f32x4 ar = *(const f32x4*)(attn_r + i);
    float v0 = bf2f(u[0]), v1 = bf2f(u[1]), v2 = bf2f(u[2]), v3 = bf2f(u[3]);
    float sl = v0 * al[0] + v1 * al[1] + v2 * al[2] + v3 * al[3];
    float sr = v0 * ar[0] + v1 * ar[1] + v2 * ar[2] + v3 * ar[3];
#pragma unroll
    for (int mask = 1; mask < 16; mask <<= 1) {
        sl += __shfl_xor(sl, mask, 64);
        sr += __shfl_xor(sr, mask, 64);
    }
    if ((lane & 15) == 0) {
        el[n * 4 + (lane >> 4)] = sl;
        er[n * 4 + (lane >> 4)] = sr;
    }
}

// ---------------------------------------------------------------------------
// K3: Lg/Lb partials (pw/nw on the fly)
// ---------------------------------------------------------------------------
__global__ __launch_bounds__(256) void loss_kernel(const int* __restrict__ src,
                                                   const int* __restrict__ dst,
                                                   const int* __restrict__ perm,
                                                   const int* __restrict__ label,
                                                   const float* __restrict__ el,
                                                   const float* __restrict__ er,
                                                   float* __restrict__ partials) {
    const int wave = threadIdx.x >> 6;
    const int lane = threadIdx.x & 63;
    const int n = blockIdx.x * 4 + wave;
    const int a = lane >> 2;
    const int h = lane & 3;
    const int e = n * DEG + a;
    const int s = src[e];
    const int d = dst[e];
    const int p = perm[e];
    const int nd = dst[p];
    const float els = el[s * 4 + h];
    const float pwa = leaky(els + er[d * 4 + h]);
    const float nwa = leaky(els + er[nd * 4 + h]);
    const int adja = (label[s] == label[d]) ? 1 : 0;
    float lg = 0.f, lb = 0.f;
#pragma unroll
    for (int b = 0; b < 16; ++b) {
        const int srcl = b * 4 + h;
        float pwb = __shfl(pwa, srcl, 64);
        int adjb = __shfl(adja, srcl, 64);
        lg += fmaxf(nwa + GMARG - pwb, 0.f);
        if (adja && !adjb) lb += fmaxf(pwb + CMARG - pwa, 0.f);
    }
#pragma unroll
    for (int mask = 1; mask < 64; mask <<= 1) {
        lg += __shfl_xor(lg, mask, 64);
        lb += __shfl_xor(lb, mask, 64);
    }
    __shared__ float slg[4], slb[4];
    if (lane == 0) { slg[wave] = lg; slb[wave] = lb; }
    __syncthreads();
    if (threadIdx.x == 0) {
        partials[blockIdx.x * 2]     = slg[0] + slg[1] + slg[2] + slg[3];
        partials[blockIdx.x * 2 + 1] = slb[0] + slb[1] + slb[2] + slb[3];
    }
}

// ---------------------------------------------------------------------------
// K4: softmax over DEG + gather-sum -> rst (FP32 out)
// ---------------------------------------------------------------------------
__global__ __launch_bounds__(256) void aggregate_kernel(const int* __restrict__ src,
                                                        const float* __restrict__ el,
                                                        const float* __restrict__ er,
                                                        const unsigned short* __restrict__ fsb,
                                                        float* __restrict__ out) {
    __shared__ float a_sm[DEG * HEADS];
    __shared__ int sidx[DEG];
    const int n = blockIdx.x;
    const int tid = threadIdx.x;
    if (tid < DEG) sidx[tid] = src[n * DEG + tid];
    __syncthreads();
    if (tid < 64) {
        const int j = tid >> 2, h = tid & 3;
        a_sm[j * 4 + h] = leaky(el[sidx[j] * 4 + h] + er[n * 4 + h]);
    }
    __syncthreads();
    if (tid < HEADS) {
        const int h = tid;
        float mx = -1e30f;
#pragma unroll
        for (int j = 0; j < DEG; ++j) mx = fmaxf(mx, a_sm[j * 4 + h]);
        float s = 0.f;
#pragma unroll
        for (int j = 0; j < DEG; ++j) {
            float ee = __expf(a_sm[j * 4 + h] - mx);
            a_sm[j * 4 + h] = ee;
            s += ee;
        }
        const float inv = 1.f / s;
#pragma unroll
        for (int j = 0; j < DEG; ++j) a_sm[j * 4 + h] *= inv;
    }
    __syncthreads();
    const int h = tid >> 6;
    float acc = 0.f;
#pragma unroll
    for (int j = 0; j < DEG; ++j) {
        acc += a_sm[j * 4 + h] * bf2f(fsb[(size_t)sidx[j] * HD + tid]);
    }
    out[(size_t)n * HD + tid] = acc;   // FP32 output
}

// ---------------------------------------------------------------------------
// K5: reduce partials -> Lg, Lb (FP32 scalars; double accumulation)
// ---------------------------------------------------------------------------
__global__ __launch_bounds__(256) void finalize_kernel(const float* __restrict__ partials,
                                                       float* __restrict__ out) {
    const int tid = threadIdx.x;
    const int lane = tid & 63;
    const int wave = tid >> 6;
    double lg = 0.0, lb = 0.0;
    for (int i = tid; i < NUM_LOSS_BLOCKS; i += 256) {
        lg += (double)partials[i * 2];
        lb += (double)partials[i * 2 + 1];
    }
#pragma unroll
    for (int mask = 1; mask < 64; mask <<= 1) {
        lg += __shfl_xor(lg, mask, 64);
        lb += __shfl_xor(lb, mask, 64);
    }
    __shared__ double slg[4], slb[4];
    if (lane == 0) { slg[wave] = lg; slb[wave] = lb; }
    __syncthreads();
    if (tid == 0) {
        const double scale = 1.0 / (double)((size_t)N_NODES * HEADS);
        out[(size_t)N_NODES * HD]     = (float)((slg[0] + slg[1] + slg[2] + slg[3]) * scale);
        out[(size_t)N_NODES * HD + 1] = (float)((slb[0] + slb[1] + slb[2] + slb[3]) * scale);
    }
}

extern "C" void kernel_launch(void* const* d_in, const int* in_sizes, int n_in,
                              void* d_out, int out_size, void* d_ws, size_t ws_size,
                              hipStream_t stream) {
    const float* feat   = (const float*)d_in[0];
    const int*   label  = (const int*)d_in[1];
    const int*   src    = (const int*)d_in[2];
    const int*   dst    = (const int*)d_in[3];
    const int*   perm   = (const int*)d_in[4];
    const float* W      = (const float*)d_in[5];
    const float* attn_l = (const float*)d_in[6];
    const float* attn_r = (const float*)d_in[7];
    float* out = (float*)d_out;   // FP32 output

    const int expect[8] = {8388608, 32768, 524288, 524288, 524288, 65536, 256, 256};
    if (n_in != 8) {
        hipLaunchKernelGGL(badcfg_kernel, dim3(1), dim3(1), 0, stream, out, 60000.f);
        return;
    }
    for (int i = 0; i < 8; ++i) {
        if (in_sizes[i] != expect[i]) {
            hipLaunchKernelGGL(badcfg_kernel, dim3(1), dim3(1), 0, stream, out,
                               65536.f + 256.f * (float)i);
            return;
        }
    }
    if (out_size != N_NODES * HD + 2) {
        hipLaunchKernelGGL(badcfg_kernel, dim3(1), dim3(1), 0, stream, out, 200000.f);
        return;
    }

    char* ws = (char*)d_ws;
    size_t off = 0;
    float* partials = (float*)(ws + off); off += (size_t)NUM_LOSS_BLOCKS * 2 * sizeof(float);
    off = (off + 255) & ~(size_t)255;
    short* Wb = (short*)(ws + off); off += (size_t)HD * HD * sizeof(short);
    off = (off + 255) & ~(size_t)255;
    unsigned short* fsb = (unsigned short*)(ws + off); off += (size_t)N_NODES * HD * sizeof(unsigned short);
    float* el = (float*)(ws + off); off += (size_t)N_NODES * HEADS * sizeof(float);
    float* er = (float*)(ws + off); off += (size_t)N_NODES * HEADS * sizeof(float);
    if (off > ws_size) {
        hipLaunchKernelGGL(badcfg_kernel, dim3(1), dim3(1), 0, stream, out, 131072.f);
        return;
    }

    hipLaunchKernelGGL(convw_kernel, dim3(HD * HD / 1024), dim3(256), 0, stream, W, Wb);
    hipLaunchKernelGGL(gemm_kernel, dim3(N_NODES / 64), dim3(256), 0, stream, feat, Wb, fsb);
    hipLaunchKernelGGL(elr_kernel, dim3(N_NODES / 4), dim3(256), 0, stream, fsb, attn_l, attn_r, el, er);
    hipLaunchKernelGGL(loss_kernel, dim3(NUM_LOSS_BLOCKS), dim3(256), 0, stream, src, dst, perm, label, el, er, partials);
    hipLaunchKernelGGL(aggregate_kernel, dim3(N_NODES), dim3(256), 0, stream, src, el, er, fsb, out);
    hipLaunchKernelGGL(finalize_kernel, dim3(1), dim3(256), 0, stream, partials, out);
}

// Round 10
// 197.541 us; speedup vs baseline: 1.6278x; 1.0479x over previous
//
#include <hip/hip_runtime.h>
#include <hip/hip_bf16.h>

#define N_NODES 32768
#define DEG 16
#define E_EDGES (N_NODES * DEG)
#define HEADS 4
#define OUT_D 64
#define HD 256            // HEADS*OUT_D
#define SLOPE 0.2f
#define GMARG 0.1f
#define CMARG 0.1f
#define NUM_LOSS_BLOCKS 8192   // N_NODES/4

typedef float f32x4 __attribute__((ext_vector_type(4)));
typedef unsigned short ushort4v __attribute__((ext_vector_type(4)));
typedef short bf16x8 __attribute__((ext_vector_type(8)));
typedef short short4v __attribute__((ext_vector_type(4)));

__device__ __forceinline__ float bf2f(unsigned short u) {
    return __uint_as_float(((unsigned int)u) << 16);
}
__device__ __forceinline__ unsigned short f2bf(float x) {
    __hip_bfloat16 h = __float2bfloat16(x);   // RNE
    return __builtin_bit_cast(unsigned short, h);
}
__device__ __forceinline__ short f2bf_s(float x) {
    __hip_bfloat16 h = __float2bfloat16(x);
    return __builtin_bit_cast(short, h);
}
__device__ __forceinline__ float leaky(float x) {
    return x >= 0.f ? x : SLOPE * x;
}

__global__ void badcfg_kernel(float* out, float code) {
    out[0] = code;
}

// ---------------------------------------------------------------------------
// K0: convert W [256,256] fp32 -> bf16 (into ws)
// ---------------------------------------------------------------------------
__global__ __launch_bounds__(256) void convw_kernel(const float* __restrict__ W,
                                                    short* __restrict__ Wb) {
    const int i = (blockIdx.x * 256 + threadIdx.x) * 4;
    f32x4 v = *(const f32x4*)(W + i);
    short4v o;
    o[0] = f2bf_s(v[0]); o[1] = f2bf_s(v[1]); o[2] = f2bf_s(v[2]); o[3] = f2bf_s(v[3]);
    *(short4v*)(Wb + i) = o;
}

// ---------------------------------------------------------------------------
// K1: fs = feat @ W^T via MFMA 16x16x32 bf16 + FUSED el/er epilogue.
// Wave = 16 nodes x 256 cols. D: row=q*4+r, col=t*16+m (m=lane&15,q=lane>>4).
// el[n,h] = sum_c fs[n][c]*attn_l[c]: per-lane partial over t (c=t*16+m),
// 16-lane xor-reduce over m, lane m=(h*4+r) writes (node=row0+q*4+r, h).
// ---------------------------------------------------------------------------
__global__ __launch_bounds__(256) void gemm_kernel(const float* __restrict__ feat,
                                                   const short* __restrict__ Wb,
                                                   const float* __restrict__ attn_l,
                                                   const float* __restrict__ attn_r,
                                                   unsigned short* __restrict__ fsb,
                                                   float* __restrict__ el,
                                                   float* __restrict__ er) {
    __shared__ float s_al[HD], s_ar[HD];
    const int tid = threadIdx.x;
    s_al[tid] = attn_l[tid];
    s_ar[tid] = attn_r[tid];

    const int wave = tid >> 6;
    const int lane = tid & 63;
    const int row0 = (blockIdx.x * 4 + wave) * 16;
    const int m = lane & 15;
    const int q = lane >> 4;

    // preload all 8 A fragments (K = 256 = 8 * 32), fp32 -> bf16 in-register
    bf16x8 afr[8];
    const float* arow = feat + (size_t)(row0 + m) * HD + q * 8;
#pragma unroll
    for (int kk = 0; kk < 8; ++kk) {
        f32x4 lo = *(const f32x4*)(arow + kk * 32);
        f32x4 hi = *(const f32x4*)(arow + kk * 32 + 4);
        bf16x8 a;
        a[0] = f2bf_s(lo[0]); a[1] = f2bf_s(lo[1]); a[2] = f2bf_s(lo[2]); a[3] = f2bf_s(lo[3]);
        a[4] = f2bf_s(hi[0]); a[5] = f2bf_s(hi[1]); a[6] = f2bf_s(hi[2]); a[7] = f2bf_s(hi[3]);
        afr[kk] = a;
    }

    f32x4 acc[16];
#pragma unroll
    for (int t = 0; t < 16; ++t) acc[t] = (f32x4)(0.0f);

#pragma unroll
    for (int t = 0; t < 16; ++t) {
        const short* brow = Wb + (size_t)(t * 16 + m) * HD + q * 8;
#pragma unroll
        for (int kk = 0; kk < 8; ++kk) {
            bf16x8 bfr = *(const bf16x8*)(brow + kk * 32);
            acc[t] = __builtin_amdgcn_mfma_f32_16x16x32_bf16(afr[kk], bfr, acc[t], 0, 0, 0);
        }
    }

    // store fs (bf16)
#pragma unroll
    for (int t = 0; t < 16; ++t) {
#pragma unroll
        for (int r = 0; r < 4; ++r) {
            fsb[(size_t)(row0 + q * 4 + r) * HD + t * 16 + m] = f2bf(acc[t][r]);
        }
    }

    // fused el/er epilogue
    __syncthreads();   // s_al/s_ar visible
    float pel[4][4], per_[4][4];   // [h][r]
#pragma unroll
    for (int h = 0; h < 4; ++h)
#pragma unroll
        for (int r = 0; r < 4; ++r) { pel[h][r] = 0.f; per_[h][r] = 0.f; }
#pragma unroll
    for (int t = 0; t < 16; ++t) {
        const float al = s_al[t * 16 + m];
        const float ar = s_ar[t * 16 + m];
        const int h = t >> 2;
#pragma unroll
        for (int r = 0; r < 4; ++r) {
            pel[h][r] += acc[t][r] * al;
            per_[h][r] += acc[t][r] * ar;
        }
    }
#pragma unroll
    for (int mask = 1; mask < 16; mask <<= 1) {
#pragma unroll
        for (int h = 0; h < 4; ++h)
#pragma unroll
            for (int r = 0; r < 4; ++r) {
                pel[h][r] += __shfl_xor(pel[h][r], mask, 64);
                per_[h][r] += __shfl_xor(per_[h][r], mask, 64);
            }
    }
    // lane m = h*4+r writes node row0+q*4+r, head h
    const int hh = m >> 2, rr = m & 3;
    float vel = 0.f, ver = 0.f;
#pragma unroll
    for (int h = 0; h < 4; ++h)
#pragma unroll
        for (int r = 0; r < 4; ++r)
            if (hh == h && rr == r) { vel = pel[h][r]; ver = per_[h][r]; }
    const int node = row0 + q * 4 + rr;
    el[node * 4 + hh] = vel;
    er[node * 4 + hh] = ver;
}

// ---------------------------------------------------------------------------
// K3: Lg/Lb partials. Analytic dst: d = e>>4 (R4 HW-verified), nd = perm[e]>>4.
// ---------------------------------------------------------------------------
__global__ __launch_bounds__(256) void loss_kernel(const int* __restrict__ src,
                                                   const int* __restrict__ perm,
                                                   const int* __restrict__ label,
                                                   const float* __restrict__ el,
                                                   const float* __restrict__ er,
                                                   float* __restrict__ partials) {
    const int wave = threadIdx.x >> 6;
    const int lane = threadIdx.x & 63;
    const int n = blockIdx.x * 4 + wave;
    const int a = lane >> 2;
    const int h = lane & 3;
    const int e = n * DEG + a;
    const int s = src[e];
    const int nd = perm[e] >> 4;          // dst[perm[e]] == perm[e]>>4
    const float els = el[s * 4 + h];
    const float pwa = leaky(els + er[n * 4 + h]);    // dst[e]==n
    const float nwa = leaky(els + er[nd * 4 + h]);
    const int adja = (label[s] == label[n]) ? 1 : 0;
    float lg = 0.f, lb = 0.f;
#pragma unroll
    for (int b = 0; b < 16; ++b) {
        const int srcl = b * 4 + h;
        float pwb = __shfl(pwa, srcl, 64);
        int adjb = __shfl(adja, srcl, 64);
        lg += fmaxf(nwa + GMARG - pwb, 0.f);
        if (adja && !adjb) lb += fmaxf(pwb + CMARG - pwa, 0.f);
    }
#pragma unroll
    for (int mask = 1; mask < 64; mask <<= 1) {
        lg += __shfl_xor(lg, mask, 64);
        lb += __shfl_xor(lb, mask, 64);
    }
    __shared__ float slg[4], slb[4];
    if (lane == 0) { slg[wave] = lg; slb[wave] = lb; }
    __syncthreads();
    if (threadIdx.x == 0) {
        partials[blockIdx.x * 2]     = slg[0] + slg[1] + slg[2] + slg[3];
        partials[blockIdx.x * 2 + 1] = slb[0] + slb[1] + slb[2] + slb[3];
    }
}

// ---------------------------------------------------------------------------
// K4: softmax + gather-sum -> rst fp32. Wave per node; lane = 4 channels.
// In-wave softmax over j via xor masks 4/8/16/32 (lane = j*4+h).
// ---------------------------------------------------------------------------
__global__ __launch_bounds__(256) void aggregate_kernel(const int* __restrict__ src,
                                                        const float* __restrict__ el,
                                                        const float* __restrict__ er,
                                                        const unsigned short* __restrict__ fsb,
                                                        float* __restrict__ out) {
    __shared__ float a_sm[4][64];   // [wave][j*4+h]
    __shared__ int sidx[4][16];
    const int tid = threadIdx.x;
    const int wave = tid >> 6;
    const int lane = tid & 63;
    const int n = blockIdx.x * 4 + wave;

    if (lane < DEG) sidx[wave][lane] = src[n * DEG + lane];
    __syncthreads();

    {   // lane = j*4 + h
        const int j = lane >> 2, h = lane & 3;
        float a = leaky(el[sidx[wave][j] * 4 + h] + er[n * 4 + h]);
        float mx = a;
#pragma unroll
        for (int mask = 4; mask < 64; mask <<= 1)
            mx = fmaxf(mx, __shfl_xor(mx, mask, 64));
        float ee = __expf(a - mx);
        float s = ee;
#pragma unroll
        for (int mask = 4; mask < 64; mask <<= 1)
            s += __shfl_xor(s, mask, 64);
        a_sm[wave][lane] = ee / s;
    }
    __syncthreads();

    const int h2 = lane >> 4;            // channel group c = lane*4.., head = c>>6
    f32x4 acc = (f32x4)(0.f);
#pragma unroll
    for (int j = 0; j < DEG; ++j) {
        const float aw = a_sm[wave][j * 4 + h2];
        ushort4v u = *(const ushort4v*)(fsb + (size_t)sidx[wave][j] * HD + lane * 4);
        acc[0] += aw * bf2f(u[0]);
        acc[1] += aw * bf2f(u[1]);
        acc[2] += aw * bf2f(u[2]);
        acc[3] += aw * bf2f(u[3]);
    }
    *(f32x4*)(out + (size_t)n * HD + lane * 4) = acc;
}

// ---------------------------------------------------------------------------
// K5: reduce partials -> Lg, Lb (fp32 scalars; double accumulation)
// ---------------------------------------------------------------------------
__global__ __launch_bounds__(256) void finalize_kernel(const float* __restrict__ partials,
                                                       float* __restrict__ out) {
    const int tid = threadIdx.x;
    const int lane = tid & 63;
    const int wave = tid >> 6;
    double lg = 0.0, lb = 0.0;
    for (int i = tid; i < NUM_LOSS_BLOCKS; i += 256) {
        lg += (double)partials[i * 2];
        lb += (double)partials[i * 2 + 1];
    }
#pragma unroll
    for (int mask = 1; mask < 64; mask <<= 1) {
        lg += __shfl_xor(lg, mask, 64);
        lb += __shfl_xor(lb, mask, 64);
    }
    __shared__ double slg[4], slb[4];
    if (lane == 0) { slg[wave] = lg; slb[wave] = lb; }
    __syncthreads();
    if (tid == 0) {
        const double scale = 1.0 / (double)((size_t)N_NODES * HEADS);
        out[(size_t)N_NODES * HD]     = (float)((slg[0] + slg[1] + slg[2] + slg[3]) * scale);
        out[(size_t)N_NODES * HD + 1] = (float)((slb[0] + slb[1] + slb[2] + slb[3]) * scale);
    }
}

extern "C" void kernel_launch(void* const* d_in, const int* in_sizes, int n_in,
                              void* d_out, int out_size, void* d_ws, size_t ws_size,
                              hipStream_t stream) {
    const float* feat   = (const float*)d_in[0];
    const int*   label  = (const int*)d_in[1];
    const int*   src    = (const int*)d_in[2];
    const int*   perm   = (const int*)d_in[4];
    const float* W      = (const float*)d_in[5];
    const float* attn_l = (const float*)d_in[6];
    const float* attn_r = (const float*)d_in[7];
    float* out = (float*)d_out;   // FP32 output

    const int expect[8] = {8388608, 32768, 524288, 524288, 524288, 65536, 256, 256};
    if (n_in != 8) {
        hipLaunchKernelGGL(badcfg_kernel, dim3(1), dim3(1), 0, stream, out, 60000.f);
        return;
    }
    for (int i = 0; i < 8; ++i) {
        if (in_sizes[i] != expect[i]) {
            hipLaunchKernelGGL(badcfg_kernel, dim3(1), dim3(1), 0, stream, out,
                               65536.f + 256.f * (float)i);
            return;
        }
    }
    if (out_size != N_NODES * HD + 2) {
        hipLaunchKernelGGL(badcfg_kernel, dim3(1), dim3(1), 0, stream, out, 200000.f);
        return;
    }

    char* ws = (char*)d_ws;
    size_t off = 0;
    float* partials = (float*)(ws + off); off += (size_t)NUM_LOSS_BLOCKS * 2 * sizeof(float);
    off = (off + 255) & ~(size_t)255;
    short* Wb = (short*)(ws + off); off += (size_t)HD * HD * sizeof(short);
    off = (off + 255) & ~(size_t)255;
    unsigned short* fsb = (unsigned short*)(ws + off); off += (size_t)N_NODES * HD * sizeof(unsigned short);
    float* el = (float*)(ws + off); off += (size_t)N_NODES * HEADS * sizeof(float);
    float* er = (float*)(ws + off); off += (size_t)N_NODES * HEADS * sizeof(float);
    if (off > ws_size) {
        hipLaunchKernelGGL(badcfg_kernel, dim3(1), dim3(1), 0, stream, out, 131072.f);
        return;
    }

    hipLaunchKernelGGL(convw_kernel, dim3(HD * HD / 1024), dim3(256), 0, stream, W, Wb);
    hipLaunchKernelGGL(gemm_kernel, dim3(N_NODES / 64), dim3(256), 0, stream,
                       feat, Wb, attn_l, attn_r, fsb, el, er);
    hipLaunchKernelGGL(loss_kernel, dim3(NUM_LOSS_BLOCKS), dim3(256), 0, stream,
                       src, perm, label, el, er, partials);
    hipLaunchKernelGGL(aggregate_kernel, dim3(N_NODES / 4), dim3(256), 0, stream,
                       src, el, er, fsb, out);
    hipLaunchKernelGGL(finalize_kernel, dim3(1), dim3(256), 0, stream, partials, out);
}

// Round 11
// 181.945 us; speedup vs baseline: 1.7673x; 1.0857x over previous
//
#include <hip/hip_runtime.h>
#include <hip/hip_bf16.h>

#define N_NODES 32768
#define DEG 16
#define E_EDGES (N_NODES * DEG)
#define HEADS 4
#define OUT_D 64
#define HD 256            // HEADS*OUT_D
#define SLOPE 0.2f
#define GMARG 0.1f
#define CMARG 0.1f
#define NUM_LOSS_BLOCKS 8192   // N_NODES/4

typedef float f32x4 __attribute__((ext_vector_type(4)));
typedef unsigned short ushort4v __attribute__((ext_vector_type(4)));
typedef short bf16x8 __attribute__((ext_vector_type(8)));
typedef short short4v __attribute__((ext_vector_type(4)));

__device__ __forceinline__ float bf2f(unsigned short u) {
    return __uint_as_float(((unsigned int)u) << 16);
}
__device__ __forceinline__ unsigned short f2bf(float x) {
    __hip_bfloat16 h = __float2bfloat16(x);   // RNE
    return __builtin_bit_cast(unsigned short, h);
}
__device__ __forceinline__ short f2bf_s(float x) {
    __hip_bfloat16 h = __float2bfloat16(x);
    return __builtin_bit_cast(short, h);
}
__device__ __forceinline__ float leaky(float x) {
    return x >= 0.f ? x : SLOPE * x;
}

__global__ void badcfg_kernel(float* out, float code) {
    out[0] = code;
}

// ---------------------------------------------------------------------------
// K0: convert W [256,256] fp32 -> bf16 (into ws)
// ---------------------------------------------------------------------------
__global__ __launch_bounds__(256) void convw_kernel(const float* __restrict__ W,
                                                    short* __restrict__ Wb) {
    const int i = (blockIdx.x * 256 + threadIdx.x) * 4;
    f32x4 v = *(const f32x4*)(W + i);
    short4v o;
    o[0] = f2bf_s(v[0]); o[1] = f2bf_s(v[1]); o[2] = f2bf_s(v[2]); o[3] = f2bf_s(v[3]);
    *(short4v*)(Wb + i) = o;
}

// ---------------------------------------------------------------------------
// K1: fs = feat @ W^T via MFMA 16x16x32 bf16 + fused el/er epilogue.
// Grid = 512 node-tiles x 2 col-halves. Block: 64 nodes x 128 cols, 4 waves.
// Wb for this block's 128 cols staged in LDS (two 32KB k-halves), fragments
// swizzled to ((c32*8+t)*64 + lane)*16B so compute ds_read_b128 is lane
// stride-1 (conflict-free). el/er fused: col-half 0 -> heads {0,1},
// col-half 1 -> heads {2,3} (disjoint, no atomics).
// ---------------------------------------------------------------------------
__global__ __launch_bounds__(256) void gemm_kernel(const float* __restrict__ feat,
                                                   const short* __restrict__ Wb,
                                                   const float* __restrict__ attn_l,
                                                   const float* __restrict__ attn_r,
                                                   unsigned short* __restrict__ fsb,
                                                   float* __restrict__ el,
                                                   float* __restrict__ er) {
    __shared__ short s_b[16384];        // 32KB: one k-half of this block's Wb
    __shared__ float s_al[128], s_ar[128];

    const int tid = threadIdx.x;
    const int node_tile = blockIdx.x >> 1;
    const int colhalf = blockIdx.x & 1;
    const int colbase = colhalf * 128;

    if (tid < 128) {
        s_al[tid] = attn_l[colbase + tid];
        s_ar[tid] = attn_r[colbase + tid];
    }

    const int wave = tid >> 6;
    const int lane = tid & 63;
    const int row0 = (node_tile * 4 + wave) * 16;
    const int m = lane & 15;
    const int q = lane >> 4;

    // preload all 8 A fragments (K = 256 = 8 * 32), fp32 -> bf16 in-register
    bf16x8 afr[8];
    const float* arow = feat + (size_t)(row0 + m) * HD + q * 8;
#pragma unroll
    for (int kk = 0; kk < 8; ++kk) {
        f32x4 lo = *(const f32x4*)(arow + kk * 32);
        f32x4 hi = *(const f32x4*)(arow + kk * 32 + 4);
        bf16x8 a;
        a[0] = f2bf_s(lo[0]); a[1] = f2bf_s(lo[1]); a[2] = f2bf_s(lo[2]); a[3] = f2bf_s(lo[3]);
        a[4] = f2bf_s(hi[0]); a[5] = f2bf_s(hi[1]); a[6] = f2bf_s(hi[2]); a[7] = f2bf_s(hi[3]);
        afr[kk] = a;
    }

    f32x4 acc[8];                       // t_local = 0..7 (128 cols)
#pragma unroll
    for (int t = 0; t < 8; ++t) acc[t] = (f32x4)(0.0f);

#pragma unroll
    for (int khalf = 0; khalf < 2; ++khalf) {
        // ---- stage this k-half of the block's Wb cols into swizzled LDS ----
        __syncthreads();                // previous compute done before overwrite
#pragma unroll
        for (int it = 0; it < 8; ++it) {
            const int u = it * 256 + tid;        // 16B unit index, 0..2047
            const int c_local = u >> 4;          // 0..127
            const int kg = u & 15;               // 0..15
            const int t_l = c_local >> 4;        // 0..7
            const int mm = c_local & 15;
            const int c32 = kg >> 2;             // 0..3
            const int qq = kg & 3;
            const int kelem = khalf * 128 + c32 * 32 + qq * 8;
            bf16x8 v = *(const bf16x8*)(Wb + (size_t)(colbase + c_local) * HD + kelem);
            *(bf16x8*)(s_b + (((c32 * 8 + t_l) * 64) + qq * 16 + mm) * 8) = v;
        }
        __syncthreads();

        // ---- MFMA from LDS: 32 ds_read_b128 + 32 MFMA per wave ----
#pragma unroll
        for (int c32 = 0; c32 < 4; ++c32) {
            const bf16x8 af = afr[khalf * 4 + c32];
#pragma unroll
            for (int t = 0; t < 8; ++t) {
                bf16x8 bfr = *(const bf16x8*)(s_b + (((c32 * 8 + t) * 64) + lane) * 8);
                acc[t] = __builtin_amdgcn_mfma_f32_16x16x32_bf16(af, bfr, acc[t], 0, 0, 0);
            }
        }
    }

    // ---- store fs (bf16): col = colbase + t*16 + m; node = row0 + q*4 + r ----
#pragma unroll
    for (int t = 0; t < 8; ++t) {
#pragma unroll
        for (int r = 0; r < 4; ++r) {
            fsb[(size_t)(row0 + q * 4 + r) * HD + colbase + t * 16 + m] = f2bf(acc[t][r]);
        }
    }

    // ---- fused el/er epilogue (this col-half covers heads colhalf*2 + {0,1}) ----
    float pel[2][4], per_[2][4];
#pragma unroll
    for (int hl = 0; hl < 2; ++hl)
#pragma unroll
        for (int r = 0; r < 4; ++r) { pel[hl][r] = 0.f; per_[hl][r] = 0.f; }
#pragma unroll
    for (int t = 0; t < 8; ++t) {
        const float al = s_al[t * 16 + m];
        const float ar = s_ar[t * 16 + m];
        const int hl = t >> 2;
#pragma unroll
        for (int r = 0; r < 4; ++r) {
            pel[hl][r] += acc[t][r] * al;
            per_[hl][r] += acc[t][r] * ar;
        }
    }
#pragma unroll
    for (int mask = 1; mask < 16; mask <<= 1) {
#pragma unroll
        for (int hl = 0; hl < 2; ++hl)
#pragma unroll
            for (int r = 0; r < 4; ++r) {
                pel[hl][r] += __shfl_xor(pel[hl][r], mask, 64);
                per_[hl][r] += __shfl_xor(per_[hl][r], mask, 64);
            }
    }
    if (m < 8) {                         // lane m = hl*4 + r
        const int hl = m >> 2, r = m & 3;
        const int hg = colhalf * 2 + hl;
        const int node = row0 + q * 4 + r;
        const float vel = (hl == 0) ? pel[0][r] : pel[1][r];
        const float ver = (hl == 0) ? per_[0][r] : per_[1][r];
        el[node * 4 + hg] = vel;
        er[node * 4 + hg] = ver;
    }
}

// ---------------------------------------------------------------------------
// K3: Lg/Lb partials. Analytic dst: d = e>>4 (R4 HW-verified), nd = perm[e]>>4.
// ---------------------------------------------------------------------------
__global__ __launch_bounds__(256) void loss_kernel(const int* __restrict__ src,
                                                   const int* __restrict__ perm,
                                                   const int* __restrict__ label,
                                                   const float* __restrict__ el,
                                                   const float* __restrict__ er,
                                                   float* __restrict__ partials) {
    const int wave = threadIdx.x >> 6;
    const int lane = threadIdx.x & 63;
    const int n = blockIdx.x * 4 + wave;
    const int a = lane >> 2;
    const int h = lane & 3;
    const int e = n * DEG + a;
    const int s = src[e];
    const int nd = perm[e] >> 4;          // dst[perm[e]] == perm[e]>>4
    const float els = el[s * 4 + h];
    const float pwa = leaky(els + er[n * 4 + h]);    // dst[e]==n
    const float nwa = leaky(els + er[nd * 4 + h]);
    const int adja = (label[s] == label[n]) ? 1 : 0;
    float lg = 0.f, lb = 0.f;
#pragma unroll
    for (int b = 0; b < 16; ++b) {
        const int srcl = b * 4 + h;
        float pwb = __shfl(pwa, srcl, 64);
        int adjb = __shfl(adja, srcl, 64);
        lg += fmaxf(nwa + GMARG - pwb, 0.f);
        if (adja && !adjb) lb += fmaxf(pwb + CMARG - pwa, 0.f);
    }
#pragma unroll
    for (int mask = 1; mask < 64; mask <<= 1) {
        lg += __shfl_xor(lg, mask, 64);
        lb += __shfl_xor(lb, mask, 64);
    }
    __shared__ float slg[4], slb[4];
    if (lane == 0) { slg[wave] = lg; slb[wave] = lb; }
    __syncthreads();
    if (threadIdx.x == 0) {
        partials[blockIdx.x * 2]     = slg[0] + slg[1] + slg[2] + slg[3];
        partials[blockIdx.x * 2 + 1] = slb[0] + slb[1] + slb[2] + slb[3];
    }
}

// ---------------------------------------------------------------------------
// K4: softmax + gather-sum -> rst fp32. Wave per node; lane = 4 channels.
// ---------------------------------------------------------------------------
__global__ __launch_bounds__(256) void aggregate_kernel(const int* __restrict__ src,
                                                        const float* __restrict__ el,
                                                        const float* __restrict__ er,
                                                        const unsigned short* __restrict__ fsb,
                                                        float* __restrict__ out) {
    __shared__ float a_sm[4][64];   // [wave][j*4+h]
    __shared__ int sidx[4][16];
    const int tid = threadIdx.x;
    const int wave = tid >> 6;
    const int lane = tid & 63;
    const int n = blockIdx.x * 4 + wave;

    if (lane < DEG) sidx[wave][lane] = src[n * DEG + lane];
    __syncthreads();

    {   // lane = j*4 + h
        const int j = lane >> 2, h = lane & 3;
        float a = leaky(el[sidx[wave][j] * 4 + h] + er[n * 4 + h]);
        float mx = a;
#pragma unroll
        for (int mask = 4; mask < 64; mask <<= 1)
            mx = fmaxf(mx, __shfl_xor(mx, mask, 64));
        float ee = __expf(a - mx);
        float s = ee;
#pragma unroll
        for (int mask = 4; mask < 64; mask <<= 1)
            s += __shfl_xor(s, mask, 64);
        a_sm[wave][lane] = ee / s;
    }
    __syncthreads();

    const int h2 = lane >> 4;
    f32x4 acc = (f32x4)(0.f);
#pragma unroll
    for (int j = 0; j < DEG; ++j) {
        const float aw = a_sm[wave][j * 4 + h2];
        ushort4v u = *(const ushort4v*)(fsb + (size_t)sidx[wave][j] * HD + lane * 4);
        acc[0] += aw * bf2f(u[0]);
        acc[1] += aw * bf2f(u[1]);
        acc[2] += aw * bf2f(u[2]);
        acc[3] += aw * bf2f(u[3]);
    }
    *(f32x4*)(out + (size_t)n * HD + lane * 4) = acc;
}

// ---------------------------------------------------------------------------
// K5: reduce partials -> Lg, Lb (fp32 scalars; double accumulation)
// ---------------------------------------------------------------------------
__global__ __launch_bounds__(256) void finalize_kernel(const float* __restrict__ partials,
                                                       float* __restrict__ out) {
    const int tid = threadIdx.x;
    const int lane = tid & 63;
    const int wave = tid >> 6;
    double lg = 0.0, lb = 0.0;
    for (int i = tid; i < NUM_LOSS_BLOCKS; i += 256) {
        lg += (double)partials[i * 2];
        lb += (double)partials[i * 2 + 1];
    }
#pragma unroll
    for (int mask = 1; mask < 64; mask <<= 1) {
        lg += __shfl_xor(lg, mask, 64);
        lb += __shfl_xor(lb, mask, 64);
    }
    __shared__ double slg[4], slb[4];
    if (lane == 0) { slg[wave] = lg; slb[wave] = lb; }
    __syncthreads();
    if (tid == 0) {
        const double scale = 1.0 / (double)((size_t)N_NODES * HEADS);
        out[(size_t)N_NODES * HD]     = (float)((slg[0] + slg[1] + slg[2] + slg[3]) * scale);
        out[(size_t)N_NODES * HD + 1] = (float)((slb[0] + slb[1] + slb[2] + slb[3]) * scale);
    }
}

extern "C" void kernel_launch(void* const* d_in, const int* in_sizes, int n_in,
                              void* d_out, int out_size, void* d_ws, size_t ws_size,
                              hipStream_t stream) {
    const float* feat   = (const float*)d_in[0];
    const int*   label  = (const int*)d_in[1];
    const int*   src    = (const int*)d_in[2];
    const int*   perm   = (const int*)d_in[4];
    const float* W      = (const float*)d_in[5];
    const float* attn_l = (const float*)d_in[6];
    const float* attn_r = (const float*)d_in[7];
    float* out = (float*)d_out;   // FP32 output

    const int expect[8] = {8388608, 32768, 524288, 524288, 524288, 65536, 256, 256};
    if (n_in != 8) {
        hipLaunchKernelGGL(badcfg_kernel, dim3(1), dim3(1), 0, stream, out, 60000.f);
        return;
    }
    for (int i = 0; i < 8; ++i) {
        if (in_sizes[i] != expect[i]) {
            hipLaunchKernelGGL(badcfg_kernel, dim3(1), dim3(1), 0, stream, out,
                               65536.f + 256.f * (float)i);
            return;
        }
    }
    if (out_size != N_NODES * HD + 2) {
        hipLaunchKernelGGL(badcfg_kernel, dim3(1), dim3(1), 0, stream, out, 200000.f);
        return;
    }

    char* ws = (char*)d_ws;
    size_t off = 0;
    float* partials = (float*)(ws + off); off += (size_t)NUM_LOSS_BLOCKS * 2 * sizeof(float);
    off = (off + 255) & ~(size_t)255;
    short* Wb = (short*)(ws + off); off += (size_t)HD * HD * sizeof(short);
    off = (off + 255) & ~(size_t)255;
    unsigned short* fsb = (unsigned short*)(ws + off); off += (size_t)N_NODES * HD * sizeof(unsigned short);
    float* el = (float*)(ws + off); off += (size_t)N_NODES * HEADS * sizeof(float);
    float* er = (float*)(ws + off); off += (size_t)N_NODES * HEADS * sizeof(float);
    if (off > ws_size) {
        hipLaunchKernelGGL(badcfg_kernel, dim3(1), dim3(1), 0, stream, out, 131072.f);
        return;
    }

    hipLaunchKernelGGL(convw_kernel, dim3(HD * HD / 1024), dim3(256), 0, stream, W, Wb);
    hipLaunchKernelGGL(gemm_kernel, dim3(N_NODES / 64 * 2), dim3(256), 0, stream,
                       feat, Wb, attn_l, attn_r, fsb, el, er);
    hipLaunchKernelGGL(loss_kernel, dim3(NUM_LOSS_BLOCKS), dim3(256), 0, stream,
                       src, perm, label, el, er, partials);
    hipLaunchKernelGGL(aggregate_kernel, dim3(N_NODES / 4), dim3(256), 0, stream,
                       src, el, er, fsb, out);
    hipLaunchKernelGGL(finalize_kernel, dim3(1), dim3(256), 0, stream, partials, out);
}

// Round 12
// 170.768 us; speedup vs baseline: 1.8830x; 1.0654x over previous
//
#include <hip/hip_runtime.h>
#include <hip/hip_bf16.h>

#define N_NODES 32768
#define DEG 16
#define E_EDGES (N_NODES * DEG)
#define HEADS 4
#define OUT_D 64
#define HD 256            // HEADS*OUT_D
#define SLOPE 0.2f
#define GMARG 0.1f
#define CMARG 0.1f
#define LOSS_BLOCKS 2048   // N_NODES/16

typedef float f32x4 __attribute__((ext_vector_type(4)));
typedef unsigned short ushort4v __attribute__((ext_vector_type(4)));
typedef short bf16x8 __attribute__((ext_vector_type(8)));
typedef short short4v __attribute__((ext_vector_type(4)));

__device__ __forceinline__ float bf2f(unsigned short u) {
    return __uint_as_float(((unsigned int)u) << 16);
}
__device__ __forceinline__ unsigned short f2bf(float x) {
    __hip_bfloat16 h = __float2bfloat16(x);   // RNE
    return __builtin_bit_cast(unsigned short, h);
}
__device__ __forceinline__ short f2bf_s(float x) {
    __hip_bfloat16 h = __float2bfloat16(x);
    return __builtin_bit_cast(short, h);
}
__device__ __forceinline__ float leaky(float x) {
    return x >= 0.f ? x : SLOPE * x;
}

__global__ void badcfg_kernel(float* out, float code) {
    out[0] = code;
}

// ---------------------------------------------------------------------------
// K0: convert W [256,256] fp32 -> bf16 (into ws)
// ---------------------------------------------------------------------------
__global__ __launch_bounds__(256) void convw_kernel(const float* __restrict__ W,
                                                    short* __restrict__ Wb) {
    const int i = (blockIdx.x * 256 + threadIdx.x) * 4;
    f32x4 v = *(const f32x4*)(W + i);
    short4v o;
    o[0] = f2bf_s(v[0]); o[1] = f2bf_s(v[1]); o[2] = f2bf_s(v[2]); o[3] = f2bf_s(v[3]);
    *(short4v*)(Wb + i) = o;
}

// ---------------------------------------------------------------------------
// K1: fs = feat @ W^T via MFMA 16x16x32 bf16 + fused el/er epilogue.
// Grid = 512 node-tiles x 2 col-halves. Block: 64 nodes x 128 cols, 4 waves.
// Wb staged in LDS swizzled; el/er fused (col-half h-pairs disjoint).
// ---------------------------------------------------------------------------
__global__ __launch_bounds__(256) void gemm_kernel(const float* __restrict__ feat,
                                                   const short* __restrict__ Wb,
                                                   const float* __restrict__ attn_l,
                                                   const float* __restrict__ attn_r,
                                                   unsigned short* __restrict__ fsb,
                                                   float* __restrict__ el,
                                                   float* __restrict__ er) {
    __shared__ short s_b[16384];        // 32KB: one k-half of this block's Wb
    __shared__ float s_al[128], s_ar[128];

    const int tid = threadIdx.x;
    const int node_tile = blockIdx.x >> 1;
    const int colhalf = blockIdx.x & 1;
    const int colbase = colhalf * 128;

    if (tid < 128) {
        s_al[tid] = attn_l[colbase + tid];
        s_ar[tid] = attn_r[colbase + tid];
    }

    const int wave = tid >> 6;
    const int lane = tid & 63;
    const int row0 = (node_tile * 4 + wave) * 16;
    const int m = lane & 15;
    const int q = lane >> 4;

    bf16x8 afr[8];
    const float* arow = feat + (size_t)(row0 + m) * HD + q * 8;
#pragma unroll
    for (int kk = 0; kk < 8; ++kk) {
        f32x4 lo = *(const f32x4*)(arow + kk * 32);
        f32x4 hi = *(const f32x4*)(arow + kk * 32 + 4);
        bf16x8 a;
        a[0] = f2bf_s(lo[0]); a[1] = f2bf_s(lo[1]); a[2] = f2bf_s(lo[2]); a[3] = f2bf_s(lo[3]);
        a[4] = f2bf_s(hi[0]); a[5] = f2bf_s(hi[1]); a[6] = f2bf_s(hi[2]); a[7] = f2bf_s(hi[3]);
        afr[kk] = a;
    }

    f32x4 acc[8];
#pragma unroll
    for (int t = 0; t < 8; ++t) acc[t] = (f32x4)(0.0f);

#pragma unroll
    for (int khalf = 0; khalf < 2; ++khalf) {
        __syncthreads();
#pragma unroll
        for (int it = 0; it < 8; ++it) {
            const int u = it * 256 + tid;
            const int c_local = u >> 4;
            const int kg = u & 15;
            const int t_l = c_local >> 4;
            const int mm = c_local & 15;
            const int c32 = kg >> 2;
            const int qq = kg & 3;
            const int kelem = khalf * 128 + c32 * 32 + qq * 8;
            bf16x8 v = *(const bf16x8*)(Wb + (size_t)(colbase + c_local) * HD + kelem);
            *(bf16x8*)(s_b + (((c32 * 8 + t_l) * 64) + qq * 16 + mm) * 8) = v;
        }
        __syncthreads();

#pragma unroll
        for (int c32 = 0; c32 < 4; ++c32) {
            const bf16x8 af = afr[khalf * 4 + c32];
#pragma unroll
            for (int t = 0; t < 8; ++t) {
                bf16x8 bfr = *(const bf16x8*)(s_b + (((c32 * 8 + t) * 64) + lane) * 8);
                acc[t] = __builtin_amdgcn_mfma_f32_16x16x32_bf16(af, bfr, acc[t], 0, 0, 0);
            }
        }
    }

#pragma unroll
    for (int t = 0; t < 8; ++t) {
#pragma unroll
        for (int r = 0; r < 4; ++r) {
            fsb[(size_t)(row0 + q * 4 + r) * HD + colbase + t * 16 + m] = f2bf(acc[t][r]);
        }
    }

    float pel[2][4], per_[2][4];
#pragma unroll
    for (int hl = 0; hl < 2; ++hl)
#pragma unroll
        for (int r = 0; r < 4; ++r) { pel[hl][r] = 0.f; per_[hl][r] = 0.f; }
#pragma unroll
    for (int t = 0; t < 8; ++t) {
        const float al = s_al[t * 16 + m];
        const float ar = s_ar[t * 16 + m];
        const int hl = t >> 2;
#pragma unroll
        for (int r = 0; r < 4; ++r) {
            pel[hl][r] += acc[t][r] * al;
            per_[hl][r] += acc[t][r] * ar;
        }
    }
#pragma unroll
    for (int mask = 1; mask < 16; mask <<= 1) {
#pragma unroll
        for (int hl = 0; hl < 2; ++hl)
#pragma unroll
            for (int r = 0; r < 4; ++r) {
                pel[hl][r] += __shfl_xor(pel[hl][r], mask, 64);
                per_[hl][r] += __shfl_xor(per_[hl][r], mask, 64);
            }
    }
    if (m < 8) {
        const int hl = m >> 2, r = m & 3;
        const int hg = colhalf * 2 + hl;
        const int node = row0 + q * 4 + r;
        const float vel = (hl == 0) ? pel[0][r] : pel[1][r];
        const float ver = (hl == 0) ? per_[0][r] : per_[1][r];
        el[node * 4 + hg] = vel;
        er[node * 4 + hg] = ver;
    }
}

// ---------------------------------------------------------------------------
// K3: Lg/Lb partials, v2: lane = edge (all 4 heads in-lane), 16 nodes/block.
// f32x4 gathers for el[s]/er[nd]; pw/adj staged in LDS; b-loop via LDS
// broadcast (same-address, conflict-free). Analytic dst (R4 HW-verified):
// d = e>>4 = n, nd = perm[e]>>4.
// ---------------------------------------------------------------------------
__global__ __launch_bounds__(256) void loss_kernel(const int* __restrict__ src,
                                                   const int* __restrict__ perm,
                                                   const int* __restrict__ label,
                                                   const float* __restrict__ el,
                                                   const float* __restrict__ er,
                                                   float* __restrict__ partials) {
    __shared__ float s_pw[16][16][4];   // [node_local][a][h]  (4 KB)
    __shared__ int   s_adj[16][16];
    __shared__ float slg[4], slb[4];

    const int tid = threadIdx.x;
    const int wave = tid >> 6;
    const int lane = tid & 63;
    const int w = lane >> 4;            // node within wave
    const int a = lane & 15;            // edge within node
    const int nl = wave * 4 + w;        // node_local 0..15
    const int n = blockIdx.x * 16 + nl;
    const int e = n * DEG + a;

    const int s  = src[e];
    const int nd = perm[e] >> 4;        // dst[perm[e]] == perm[e]>>4
    f32x4 els  = *(const f32x4*)(el + (size_t)s * 4);
    f32x4 ern  = *(const f32x4*)(er + (size_t)n * 4);
    f32x4 ernd = *(const f32x4*)(er + (size_t)nd * 4);
    const int adja = (label[s] == label[n]) ? 1 : 0;

    f32x4 pw, nw;
#pragma unroll
    for (int h = 0; h < 4; ++h) {
        pw[h] = leaky(els[h] + ern[h]);
        nw[h] = leaky(els[h] + ernd[h]);
    }
    *(f32x4*)&s_pw[nl][a][0] = pw;
    s_adj[nl][a] = adja;
    __syncthreads();

    float lg = 0.f, lb = 0.f;
#pragma unroll
    for (int b = 0; b < 16; ++b) {
        f32x4 pwb = *(const f32x4*)&s_pw[nl][b][0];   // broadcast within node
        const int adjb = s_adj[nl][b];
#pragma unroll
        for (int h = 0; h < 4; ++h)
            lg += fmaxf(nw[h] + GMARG - pwb[h], 0.f);
        if (adja && !adjb) {
#pragma unroll
            for (int h = 0; h < 4; ++h)
                lb += fmaxf(pwb[h] + CMARG - pw[h], 0.f);
        }
    }
#pragma unroll
    for (int mask = 1; mask < 64; mask <<= 1) {
        lg += __shfl_xor(lg, mask, 64);
        lb += __shfl_xor(lb, mask, 64);
    }
    if (lane == 0) { slg[wave] = lg; slb[wave] = lb; }
    __syncthreads();
    if (tid == 0) {
        partials[blockIdx.x * 2]     = slg[0] + slg[1] + slg[2] + slg[3];
        partials[blockIdx.x * 2 + 1] = slb[0] + slb[1] + slb[2] + slb[3];
    }
}

// ---------------------------------------------------------------------------
// K4: softmax + gather-sum -> rst fp32. Wave per node; lane = 4 channels.
// ---------------------------------------------------------------------------
__global__ __launch_bounds__(256) void aggregate_kernel(const int* __restrict__ src,
                                                        const float* __restrict__ el,
                                                        const float* __restrict__ er,
                                                        const unsigned short* __restrict__ fsb,
                                                        float* __restrict__ out) {
    __shared__ float a_sm[4][64];   // [wave][j*4+h]
    __shared__ int sidx[4][16];
    const int tid = threadIdx.x;
    const int wave = tid >> 6;
    const int lane = tid & 63;
    const int n = blockIdx.x * 4 + wave;

    if (lane < DEG) sidx[wave][lane] = src[n * DEG + lane];
    __syncthreads();

    {   // lane = j*4 + h
        const int j = lane >> 2, h = lane & 3;
        float a = leaky(el[sidx[wave][j] * 4 + h] + er[n * 4 + h]);
        float mx = a;
#pragma unroll
        for (int mask = 4; mask < 64; mask <<= 1)
            mx = fmaxf(mx, __shfl_xor(mx, mask, 64));
        float ee = __expf(a - mx);
        float s = ee;
#pragma unroll
        for (int mask = 4; mask < 64; mask <<= 1)
            s += __shfl_xor(s, mask, 64);
        a_sm[wave][lane] = ee / s;
    }
    __syncthreads();

    const int h2 = lane >> 4;
    f32x4 acc = (f32x4)(0.f);
#pragma unroll
    for (int j = 0; j < DEG; ++j) {
        const float aw = a_sm[wave][j * 4 + h2];
        ushort4v u = *(const ushort4v*)(fsb + (size_t)sidx[wave][j] * HD + lane * 4);
        acc[0] += aw * bf2f(u[0]);
        acc[1] += aw * bf2f(u[1]);
        acc[2] += aw * bf2f(u[2]);
        acc[3] += aw * bf2f(u[3]);
    }
    *(f32x4*)(out + (size_t)n * HD + lane * 4) = acc;
}

// ---------------------------------------------------------------------------
// K5: reduce partials -> Lg, Lb (fp32 scalars; double accumulation)
// ---------------------------------------------------------------------------
__global__ __launch_bounds__(256) void finalize_kernel(const float* __restrict__ partials,
                                                       float* __restrict__ out) {
    const int tid = threadIdx.x;
    const int lane = tid & 63;
    const int wave = tid >> 6;
    double lg = 0.0, lb = 0.0;
    for (int i = tid; i < LOSS_BLOCKS; i += 256) {
        lg += (double)partials[i * 2];
        lb += (double)partials[i * 2 + 1];
    }
#pragma unroll
    for (int mask = 1; mask < 64; mask <<= 1) {
        lg += __shfl_xor(lg, mask, 64);
        lb += __shfl_xor(lb, mask, 64);
    }
    __shared__ double slg[4], slb[4];
    if (lane == 0) { slg[wave] = lg; slb[wave] = lb; }
    __syncthreads();
    if (tid == 0) {
        const double scale = 1.0 / (double)((size_t)N_NODES * HEADS);
        out[(size_t)N_NODES * HD]     = (float)((slg[0] + slg[1] + slg[2] + slg[3]) * scale);
        out[(size_t)N_NODES * HD + 1] = (float)((slb[0] + slb[1] + slb[2] + slb[3]) * scale);
    }
}

extern "C" void kernel_launch(void* const* d_in, const int* in_sizes, int n_in,
                              void* d_out, int out_size, void* d_ws, size_t ws_size,
                              hipStream_t stream) {
    const float* feat   = (const float*)d_in[0];
    const int*   label  = (const int*)d_in[1];
    const int*   src    = (const int*)d_in[2];
    const int*   perm   = (const int*)d_in[4];
    const float* W      = (const float*)d_in[5];
    const float* attn_l = (const float*)d_in[6];
    const float* attn_r = (const float*)d_in[7];
    float* out = (float*)d_out;   // FP32 output

    const int expect[8] = {8388608, 32768, 524288, 524288, 524288, 65536, 256, 256};
    if (n_in != 8) {
        hipLaunchKernelGGL(badcfg_kernel, dim3(1), dim3(1), 0, stream, out, 60000.f);
        return;
    }
    for (int i = 0; i < 8; ++i) {
        if (in_sizes[i] != expect[i]) {
            hipLaunchKernelGGL(badcfg_kernel, dim3(1), dim3(1), 0, stream, out,
                               65536.f + 256.f * (float)i);
            return;
        }
    }
    if (out_size != N_NODES * HD + 2) {
        hipLaunchKernelGGL(badcfg_kernel, dim3(1), dim3(1), 0, stream, out, 200000.f);
        return;
    }

    char* ws = (char*)d_ws;
    size_t off = 0;
    float* partials = (float*)(ws + off); off += (size_t)LOSS_BLOCKS * 2 * sizeof(float);
    off = (off + 255) & ~(size_t)255;
    short* Wb = (short*)(ws + off); off += (size_t)HD * HD * sizeof(short);
    off = (off + 255) & ~(size_t)255;
    unsigned short* fsb = (unsigned short*)(ws + off); off += (size_t)N_NODES * HD * sizeof(unsigned short);
    float* el = (float*)(ws + off); off += (size_t)N_NODES * HEADS * sizeof(float);
    float* er = (float*)(ws + off); off += (size_t)N_NODES * HEADS * sizeof(float);
    if (off > ws_size) {
        hipLaunchKernelGGL(badcfg_kernel, dim3(1), dim3(1), 0, stream, out, 131072.f);
        return;
    }

    hipLaunchKernelGGL(convw_kernel, dim3(HD * HD / 1024), dim3(256), 0, stream, W, Wb);
    hipLaunchKernelGGL(gemm_kernel, dim3(N_NODES / 64 * 2), dim3(256), 0, stream,
                       feat, Wb, attn_l, attn_r, fsb, el, er);
    hipLaunchKernelGGL(loss_kernel, dim3(LOSS_BLOCKS), dim3(256), 0, stream,
                       src, perm, label, el, er, partials);
    hipLaunchKernelGGL(aggregate_kernel, dim3(N_NODES / 4), dim3(256), 0, stream,
                       src, el, er, fsb, out);
    hipLaunchKernelGGL(finalize_kernel, dim3(1), dim3(256), 0, stream, partials, out);
}